// Round 3
// baseline (1679.981 us; speedup 1.0000x reference)
//
#include <hip/hip_runtime.h>
#include <hip/hip_bf16.h>

// RNN_80848464380442: B=64, S=2048, V=50257, E=128, H=256, C=2 (f32 in/out, x int32)
// Stage 1: xw[b*S+t][j] = bU[j] + sum_e emb[x[b,t]][e]*W[e][j]  (bf16 to ws, emb row0=0)
// Stage 2: MFMA scan. 8 blocks x 8 batch rows. h16 = tanh(xw_t + h @ U) via
//          mfma_f32_16x16x32_bf16, M=8 of 16 (rows 8-15 zero). U in registers as
//          B-frags (2 N-tiles/wave), h double-buffered in LDS, 1 barrier/step.
// Stage 3: logits = h @ V + bV fused in scan epilogue.

#define HB 256
#define EB 128
#define SB 2048
#define BB 64
#define TPB 16
#define ROWS 8
#define PITCH 264   // bf16 elems per H row: 528 B -> 4-bank shift/row, 2-way max (free)

typedef unsigned short u16;
typedef __attribute__((ext_vector_type(4))) float f32x4;
typedef __attribute__((ext_vector_type(8))) short bf16x8;

__device__ __forceinline__ u16 f2bf(float f) {
    union { float f; unsigned u; } x; x.f = f;
    unsigned r = x.u + 0x7fffu + ((x.u >> 16) & 1u);   // RNE
    return (u16)(r >> 16);
}
__device__ __forceinline__ float bf2f(u16 v) {
    union { unsigned u; float f; } x; x.u = ((unsigned)v) << 16; return x.f;
}

// ---------------- Stage 1: embed + project (16 tokens per 256-thread block) --------
__global__ __launch_bounds__(256) void embed_proj(
    const int* __restrict__ x, const float* __restrict__ emb,
    const float* __restrict__ W, const float* __restrict__ bU,
    u16* __restrict__ xw)
{
    __shared__ __align__(16) float el[TPB][EB];
    __shared__ int toks[TPB];

    const int tid = threadIdx.x;
    const long base = (long)blockIdx.x * TPB;

    if (tid < TPB) toks[tid] = x[base + tid];
    __syncthreads();

    #pragma unroll
    for (int r = 0; r < TPB * EB / 256; ++r) {
        int i = tid + r * 256;
        int row = i >> 7, e = i & (EB - 1);
        int u = toks[row];
        el[row][e] = (u == 0) ? 0.f : emb[(size_t)u * EB + e];   // padding_idx=0
    }
    __syncthreads();

    const int j = tid;
    const float bu = bU[j];
    float acc[TPB];
    #pragma unroll
    for (int t = 0; t < TPB; ++t) acc[t] = bu;

    for (int e0 = 0; e0 < EB; e0 += 4) {
        float w0 = W[(e0 + 0) * HB + j];
        float w1 = W[(e0 + 1) * HB + j];
        float w2 = W[(e0 + 2) * HB + j];
        float w3 = W[(e0 + 3) * HB + j];
        #pragma unroll
        for (int t = 0; t < TPB; ++t) {
            float4 ev = *(const float4*)&el[t][e0];
            acc[t] = fmaf(ev.x, w0, acc[t]);
            acc[t] = fmaf(ev.y, w1, acc[t]);
            acc[t] = fmaf(ev.z, w2, acc[t]);
            acc[t] = fmaf(ev.w, w3, acc[t]);
        }
    }
    #pragma unroll
    for (int t = 0; t < TPB; ++t)
        xw[(base + t) * HB + j] = f2bf(acc[t]);
}

// ---------------- Stage 2+3: MFMA scan, 8 blocks x 512 threads ---------------------
__global__ __launch_bounds__(512) void rnn_scan_mfma(
    const u16* __restrict__ xw, const float* __restrict__ U,
    const float* __restrict__ V, const float* __restrict__ bV,
    float* __restrict__ out)
{
    __shared__ u16 H[2][16][PITCH];   // double-buffered h (bf16), rows 8-15 stay zero

    const int tid  = threadIdx.x;
    const int lane = tid & 63;
    const int w    = tid >> 6;            // wave 0..7, owns N-tiles 2w, 2w+1
    const int b0   = blockIdx.x * ROWS;

    {   // zero both H buffers (incl. pad + rows 8-15)
        unsigned* hz = (unsigned*)H;
        for (int i = tid; i < 2 * 16 * PITCH / 2; i += 512) hz[i] = 0u;
    }

    // ---- B-frag preload: B[k][n] = U[k][n], lane%16 = n, lane/16 = k-group-of-8 ----
    const int n  = lane & 15;
    const int kg = (lane >> 4) & 3;
    bf16x8 Bf[2][8];
    #pragma unroll
    for (int s = 0; s < 2; ++s) {
        const int nt = 2 * w + s;
        #pragma unroll
        for (int ks = 0; ks < 8; ++ks) {
            const int k0 = ks * 32 + kg * 8;
            union { bf16x8 v; u16 h[8]; } tmp;
            #pragma unroll
            for (int e = 0; e < 8; ++e)
                tmp.h[e] = f2bf(U[(size_t)(k0 + e) * HB + nt * 16 + n]);
            Bf[s][ks] = tmp.v;
        }
    }

    // ---- epilogue lane mapping (after 2-tile shfl merge: all 64 lanes useful) ----
    const int side = lane >> 5;                          // 0: tile 2w, 1: tile 2w+1
    const int rr4  = ((lane >> 4) & 1) * 4;              // row base, +q
    const int col  = (lane & 15) + 16 * (2 * w + side);  // output column j
    unsigned base[4];
    u16 xwc[4];
    #pragma unroll
    for (int q = 0; q < 4; ++q) {
        base[q] = ((unsigned)(b0 + rr4 + q) * SB) * HB + col;
        xwc[q]  = xw[base[q]];                           // t = 0
    }
    __syncthreads();

    int cb = 0;
    for (int t = 0; t < SB; ++t) {
        // A-frags from H[cb]: lane%16 = m, lane/16 = k-group; rows >= 8 are zero,
        // exec-masked read halves LDS traffic.
        bf16x8 Af[8];
        const int m = lane & 15;
        #pragma unroll
        for (int ks = 0; ks < 8; ++ks) {
            uint4 av = make_uint4(0u, 0u, 0u, 0u);
            if (m < ROWS)
                av = *(const uint4*)&H[cb][m][ks * 32 + kg * 8];
            Af[ks] = __builtin_bit_cast(bf16x8, av);
        }

        // prefetch xw for t+1 (clamped to stay in-bounds on last step)
        const int tn = (t + 1 < SB) ? t + 1 : t;
        u16 xwn[4];
        #pragma unroll
        for (int q = 0; q < 4; ++q)
            xwn[q] = xw[base[q] + (unsigned)tn * HB];

        // 16 MFMAs, two independent accumulator chains
        f32x4 acc0 = {0.f, 0.f, 0.f, 0.f}, acc1 = {0.f, 0.f, 0.f, 0.f};
        #pragma unroll
        for (int ks = 0; ks < 8; ++ks) {
            acc0 = __builtin_amdgcn_mfma_f32_16x16x32_bf16(Af[ks], Bf[0][ks], acc0, 0, 0, 0);
            acc1 = __builtin_amdgcn_mfma_f32_16x16x32_bf16(Af[ks], Bf[1][ks], acc1, 0, 0, 0);
        }

        // epilogue: merge tiles so all lanes are useful, tanh, write next h
        const int nb   = cb ^ 1;
        const int srcl = lane & 31;
        #pragma unroll
        for (int q = 0; q < 4; ++q) {
            float v1 = __shfl(acc1[q], srcl);            // acc1 from lane (lane&31)
            float mv = side ? v1 : acc0[q];
            float z  = mv + bf2f(xwc[q]);
            float E  = __expf(z + z);                    // tanh = 1 - 2/(e^2z + 1)
            float rc = __builtin_amdgcn_rcpf(E + 1.0f);
            float th = fmaf(-2.0f, rc, 1.0f);
            H[nb][rr4 + q][col] = f2bf(th);
            if (t == SB - 1)
                out[BB * 2 + (size_t)(b0 + rr4 + q) * HB + col] = th;  // f32 h output
            xwc[q] = xwn[q];
        }
        cb = nb;
        __syncthreads();
    }

    // logits: h_final in H[cb] (2048 toggles -> cb == 0)
    if (tid < ROWS * 16) {
        const int r = tid >> 4, part = tid & 15;
        float s0 = 0.f, s1 = 0.f;
        #pragma unroll
        for (int i = 0; i < 16; ++i) {
            const int j = part * 16 + i;
            float hh = bf2f(H[cb][r][j]);
            s0 = fmaf(hh, V[j * 2 + 0], s0);
            s1 = fmaf(hh, V[j * 2 + 1], s1);
        }
        #pragma unroll
        for (int o = 8; o > 0; o >>= 1) {
            s0 += __shfl_down(s0, o, 16);
            s1 += __shfl_down(s1, o, 16);
        }
        if (part == 0) {
            out[(size_t)(b0 + r) * 2 + 0] = s0 + bV[0];
            out[(size_t)(b0 + r) * 2 + 1] = s1 + bV[1];
        }
    }
}

extern "C" void kernel_launch(void* const* d_in, const int* in_sizes, int n_in,
                              void* d_out, int out_size, void* d_ws, size_t ws_size,
                              hipStream_t stream) {
    const int*   x   = (const int*)d_in[0];
    const float* emb = (const float*)d_in[1];
    const float* W   = (const float*)d_in[2];
    const float* U   = (const float*)d_in[3];
    const float* bU  = (const float*)d_in[4];
    const float* V   = (const float*)d_in[5];
    const float* bV  = (const float*)d_in[6];
    float* out = (float*)d_out;
    u16*   xw  = (u16*)d_ws;   // 64 MiB bf16 scratch

    embed_proj<<<BB * SB / TPB, 256, 0, stream>>>(x, emb, W, bU, xw);
    rnn_scan_mfma<<<BB / ROWS, 512, 0, stream>>>(xw, U, V, bV, out);
}

// Round 4
// 1452.902 us; speedup vs baseline: 1.1563x; 1.1563x over previous
//
#include <hip/hip_runtime.h>
#include <hip/hip_bf16.h>

// RNN_80848464380442: B=64, S=2048, V=50257, E=128, H=256, C=2 (f32 in/out, x int32)
// Stage 1: xw[b*S+t][j] = bU[j] + sum_e emb[x[b,t]][e]*W[e][j]  (bf16 to ws, emb row0=0)
// Stage 2: MFMA scan, 4 blocks x 16 batch rows (full M=16), 8 waves x 2 N-tiles.
//          U in registers as B-frags; h double-buffered in LDS; 1 barrier/step;
//          all 64 lanes valid in D -> no shfl merge, no exec masking.
// Stage 3: logits = h @ V + bV fused in scan epilogue.

#define HB 256
#define EB 128
#define SB 2048
#define BB 64
#define TPB 32
#define ROWS 16
#define PITCH 264   // u16/row: 528 B -> 4-bank shift/row; full-16-row b128 reads uniform

typedef unsigned short u16;
typedef __attribute__((ext_vector_type(4))) float f32x4;
typedef __attribute__((ext_vector_type(8))) short bf16x8;

__device__ __forceinline__ u16 f2bf(float f) {
    union { float f; unsigned u; } x; x.f = f;
    unsigned r = x.u + 0x7fffu + ((x.u >> 16) & 1u);   // RNE
    return (u16)(r >> 16);
}
__device__ __forceinline__ float bf2f(u16 v) {
    union { unsigned u; float f; } x; x.u = ((unsigned)v) << 16; return x.f;
}

// ---------------- Stage 1: embed + project (32 tokens per 256-thread block) --------
__global__ __launch_bounds__(256) void embed_proj(
    const int* __restrict__ x, const float* __restrict__ emb,
    const float* __restrict__ W, const float* __restrict__ bU,
    u16* __restrict__ xw)
{
    __shared__ __align__(16) float el[TPB][EB];   // 16 KB
    __shared__ int toks[TPB];

    const int tid = threadIdx.x;
    const long base = (long)blockIdx.x * TPB;

    if (tid < TPB) toks[tid] = x[base + tid];
    __syncthreads();

    for (int r = 0; r < TPB * EB / 256; ++r) {
        int i = tid + r * 256;
        int row = i >> 7, e = i & (EB - 1);
        int u = toks[row];
        el[row][e] = (u == 0) ? 0.f : emb[(size_t)u * EB + e];   // padding_idx=0
    }
    __syncthreads();

    const int j = tid;
    const float bu = bU[j];
    float acc[TPB];
    #pragma unroll
    for (int t = 0; t < TPB; ++t) acc[t] = bu;

    for (int e0 = 0; e0 < EB; e0 += 4) {
        float w0 = W[(e0 + 0) * HB + j];
        float w1 = W[(e0 + 1) * HB + j];
        float w2 = W[(e0 + 2) * HB + j];
        float w3 = W[(e0 + 3) * HB + j];
        #pragma unroll
        for (int t = 0; t < TPB; ++t) {
            float4 ev = *(const float4*)&el[t][e0];
            acc[t] = fmaf(ev.x, w0, acc[t]);
            acc[t] = fmaf(ev.y, w1, acc[t]);
            acc[t] = fmaf(ev.z, w2, acc[t]);
            acc[t] = fmaf(ev.w, w3, acc[t]);
        }
    }
    #pragma unroll
    for (int t = 0; t < TPB; ++t)
        xw[(base + t) * HB + j] = f2bf(acc[t]);
}

// ---------------- Stage 2+3: MFMA scan, 4 blocks x 512 threads (8 waves) -----------
__global__ __launch_bounds__(512, 1) void rnn_scan_mfma(
    const u16* __restrict__ xw, const float* __restrict__ U,
    const float* __restrict__ V, const float* __restrict__ bV,
    float* __restrict__ out)
{
    __shared__ __align__(16) u16 H[2][ROWS][PITCH];   // double-buffered h (bf16)

    const int tid  = threadIdx.x;
    const int lane = tid & 63;
    const int w    = tid >> 6;            // wave 0..7, owns N-tiles 2w, 2w+1
    const int b0   = blockIdx.x * ROWS;

    {   // zero both H buffers (incl. pad)
        unsigned* hz = (unsigned*)H;
        for (int i = tid; i < 2 * ROWS * PITCH / 2; i += 512) hz[i] = 0u;
    }

    const int n  = lane & 15;             // tile col (B-n / A-m / D-col)
    const int kg = lane >> 4;             // 0..3 (k-group / D row-group)

    // ---- B-frag preload: Bf[s][ks], tile nt = 2w+s, elem k = ks*32 + kg*8 + e ----
    bf16x8 Bf[2][8];
    #pragma unroll
    for (int s = 0; s < 2; ++s) {
        const int nt = 2 * w + s;
        #pragma unroll
        for (int ks = 0; ks < 8; ++ks) {
            const int k0 = ks * 32 + kg * 8;
            union { bf16x8 v; u16 h[8]; } tmp;
            #pragma unroll
            for (int e = 0; e < 8; ++e)
                tmp.h[e] = f2bf(U[(size_t)(k0 + e) * HB + nt * 16 + n]);
            Bf[s][ks] = tmp.v;
        }
    }

    // ---- epilogue mapping: D row = kg*4+q (0..15), cols 32w+n and 32w+16+n ----
    unsigned base[4];
    u16 xwc[8];
    #pragma unroll
    for (int q = 0; q < 4; ++q) {
        const int rowg = b0 + kg * 4 + q;
        base[q] = ((unsigned)rowg * SB) * HB + 32 * w + n;
        xwc[2 * q + 0] = xw[base[q] + 0];     // t = 0, tile 2w
        xwc[2 * q + 1] = xw[base[q] + 16];    // t = 0, tile 2w+1
    }
    __syncthreads();

    for (int t = 0; t < SB; ++t) {
        const int cb = t & 1 ? 1 : 0;     // read buffer (h_t)
        const int nb = cb ^ 1;            // write buffer (h_{t+1})

        // prefetch xw[t+1] (in flight across the whole step body)
        const unsigned tn = (unsigned)((t + 1 < SB) ? t + 1 : t) * HB;
        u16 xwn[8];
        #pragma unroll
        for (int q = 0; q < 4; ++q) {
            xwn[2 * q + 0] = xw[base[q] + tn + 0];
            xwn[2 * q + 1] = xw[base[q] + tn + 16];
        }

        // A-frags: full 16 rows, m = n(lane&15), k = ks*32 + kg*8 .. +8
        bf16x8 Af[8];
        #pragma unroll
        for (int ks = 0; ks < 8; ++ks) {
            uint4 av = *(const uint4*)&H[cb][n][ks * 32 + kg * 8];
            Af[ks] = __builtin_bit_cast(bf16x8, av);
        }

        // 16 MFMAs, 2 independent chains
        f32x4 acc0 = {0.f, 0.f, 0.f, 0.f}, acc1 = {0.f, 0.f, 0.f, 0.f};
        #pragma unroll
        for (int ks = 0; ks < 8; ++ks) {
            acc0 = __builtin_amdgcn_mfma_f32_16x16x32_bf16(Af[ks], Bf[0][ks], acc0, 0, 0, 0);
            acc1 = __builtin_amdgcn_mfma_f32_16x16x32_bf16(Af[ks], Bf[1][ks], acc1, 0, 0, 0);
        }

        // epilogue: tanh(z) = 1 - 2/(1 + e^{2z}); all lanes useful
        #pragma unroll
        for (int q = 0; q < 4; ++q) {
            const int row = kg * 4 + q;
            float z0 = acc0[q] + bf2f(xwc[2 * q + 0]);
            float z1 = acc1[q] + bf2f(xwc[2 * q + 1]);
            float E0 = __expf(z0 + z0);
            float E1 = __expf(z1 + z1);
            float th0 = fmaf(-2.f, __builtin_amdgcn_rcpf(E0 + 1.f), 1.f);
            float th1 = fmaf(-2.f, __builtin_amdgcn_rcpf(E1 + 1.f), 1.f);
            unsigned pk;
            asm("v_cvt_pk_bf16_f32 %0, %1, %2" : "=v"(pk) : "v"(th0), "v"(th1));
            H[nb][row][32 * w + n]      = (u16)(pk & 0xffffu);
            H[nb][row][32 * w + 16 + n] = (u16)(pk >> 16);
            if (t == SB - 1) {
                out[BB * 2 + (size_t)(b0 + row) * HB + 32 * w + n]      = th0;
                out[BB * 2 + (size_t)(b0 + row) * HB + 32 * w + 16 + n] = th1;
            }
            xwc[2 * q + 0] = xwn[2 * q + 0];
            xwc[2 * q + 1] = xwn[2 * q + 1];
        }
        __syncthreads();
    }

    // logits: h_final in H[0] (SB even). 256 threads: r = tid>>4, part = tid&15
    if (tid < ROWS * 16) {
        const int r = tid >> 4, part = tid & 15;
        float s0 = 0.f, s1 = 0.f;
        #pragma unroll
        for (int i = 0; i < 16; ++i) {
            const int j = part * 16 + i;
            float hh = bf2f(H[0][r][j]);
            s0 = fmaf(hh, V[j * 2 + 0], s0);
            s1 = fmaf(hh, V[j * 2 + 1], s1);
        }
        #pragma unroll
        for (int o = 8; o > 0; o >>= 1) {
            s0 += __shfl_down(s0, o, 16);
            s1 += __shfl_down(s1, o, 16);
        }
        if (part == 0) {
            out[(size_t)(b0 + r) * 2 + 0] = s0 + bV[0];
            out[(size_t)(b0 + r) * 2 + 1] = s1 + bV[1];
        }
    }
}

extern "C" void kernel_launch(void* const* d_in, const int* in_sizes, int n_in,
                              void* d_out, int out_size, void* d_ws, size_t ws_size,
                              hipStream_t stream) {
    const int*   x   = (const int*)d_in[0];
    const float* emb = (const float*)d_in[1];
    const float* W   = (const float*)d_in[2];
    const float* U   = (const float*)d_in[3];
    const float* bU  = (const float*)d_in[4];
    const float* V   = (const float*)d_in[5];
    const float* bV  = (const float*)d_in[6];
    float* out = (float*)d_out;
    u16*   xw  = (u16*)d_ws;   // 64 MiB bf16 scratch

    embed_proj<<<BB * SB / TPB, 256, 0, stream>>>(x, emb, W, bU, xw);
    rnn_scan_mfma<<<BB / ROWS, 512, 0, stream>>>(xw, U, V, bV, out);
}